// Round 3
// baseline (193.127 us; speedup 1.0000x reference)
//
#include <hip/hip_runtime.h>

#define ALPHA 0.2f
#define B_    8
#define N_    2048
#define INF_  128
#define OUTF_ 64

typedef __attribute__((ext_vector_type(8))) short short8;
typedef __attribute__((ext_vector_type(4))) float f32x4;

__device__ __forceinline__ unsigned short f2bf(float f) {
    unsigned int x = __float_as_uint(f);
    return (unsigned short)((x + 0x7fffu + ((x >> 16) & 1u)) >> 16);
}

// Kernel A: x_w = inputs @ W  -> xwT (bf16, TRANSPOSED [B][64][N]) for MFMA
// B-fragments; s1/s2 row scores (fp32). 16 rows/block, 4 rows/wave.
__global__ __launch_bounds__(256) void prep_kernel(
    const float* __restrict__ inp,    // [B*N, 128] f32
    const float* __restrict__ nodes,  // [B*N, 64]  f32
    const float* __restrict__ Wm,     // [128, 64]  f32
    const float* __restrict__ av,     // [256]      f32
    unsigned short* __restrict__ xwT, // [B][64][N] bf16
    float* __restrict__ s1_out,       // [B*N]
    float* __restrict__ s2_out)       // [B*N]
{
    __shared__ float w_lds[INF_ * OUTF_];            // 32 KB [k][f]
    __shared__ float in_lds[16 * INF_];              // 8 KB  [r][k]
    __shared__ __align__(16) unsigned short t_lds[64 * 16];  // [n][r] bf16
    const int tid  = threadIdx.x;
    const int wave = tid >> 6, lane = tid & 63;
    const int r0   = blockIdx.x * 16;

    {
        const float4* Wv = (const float4*)Wm;        // 2048 float4
        float4* wd = (float4*)w_lds;
        #pragma unroll
        for (int q = 0; q < 8; q++) wd[tid + q * 256] = Wv[tid + q * 256];
        const float4* Iv = (const float4*)(inp + (size_t)r0 * INF_);  // 512
        float4* id4 = (float4*)in_lds;
        id4[tid]       = Iv[tid];
        id4[tid + 256] = Iv[tid + 256];
    }
    __syncthreads();

    float acc[4] = {0.f, 0.f, 0.f, 0.f};
    const float* inw = &in_lds[(wave * 4) * INF_];
    #pragma unroll 4
    for (int k = 0; k < INF_; k++) {
        float wv = w_lds[k * OUTF_ + lane];     // stride-1 across lanes
        acc[0] += inw[k]            * wv;       // broadcast reads
        acc[1] += inw[INF_ + k]     * wv;
        acc[2] += inw[2 * INF_ + k] * wv;
        acc[3] += inw[3 * INF_ + k] * wv;
    }

    const float a1n = av[lane];
    const float a1x = av[64 + lane];
    const float a2n = av[128 + lane];
    const float a2x = av[192 + lane];

    #pragma unroll
    for (int rr = 0; rr < 4; rr++) {
        const int row = r0 + wave * 4 + rr;
        float nf = nodes[(size_t)row * OUTF_ + lane];
        float p1 = nf * a1n + acc[rr] * a1x;
        float p2 = nf * a2n + acc[rr] * a2x;
        #pragma unroll
        for (int off = 32; off; off >>= 1) {
            p1 += __shfl_down(p1, off);
            p2 += __shfl_down(p2, off);
        }
        if (lane == 0) { s1_out[row] = p1; s2_out[row] = p2; }
        t_lds[lane * 16 + wave * 4 + rr] = f2bf(acc[rr]);  // transpose via LDS
    }
    __syncthreads();

    // thread t writes 4 contiguous bf16 of row n = t>>2 into xwT
    {
        const int n  = tid >> 2, c0 = (tid & 3) * 4;
        const int b  = r0 >> 11, rb = r0 & (N_ - 1);
        *(uint2*)(xwT + ((size_t)b * OUTF_ + n) * N_ + rb + c0) =
            *(const uint2*)&t_lds[n * 16 + c0];
    }
}

// Kernel C: block = 64 rows of one batch; 4 waves, wave w -> rows w*16..+16.
// Softmax stats prologue, then K-loop: att computed directly in MFMA
// A-fragment layout (A[m=lane&15][k=quad*8+jj]), B-frags = 16B global loads
// from xwT (L2-resident), fp32 att stored to global. No LDS/syncs in K-loop.
__global__ __launch_bounds__(256) void attn_kernel(
    const unsigned short* __restrict__ xwT,  // [B][64][N] bf16
    const float* __restrict__ s1g,           // [B, N]
    const float* __restrict__ s2g,           // [B, N]
    float* __restrict__ out_h,               // [B, N, 64] f32
    float* __restrict__ out_att)             // [B, N, N]  f32
{
    __shared__ float s2_lds[N_];    // 8 KB
    __shared__ float s1_lds[64];
    __shared__ float m_lds[64];
    __shared__ float li_lds[64];
    __shared__ float redmax[4];

    const int tid  = threadIdx.x;
    const int wave = tid >> 6, lane = tid & 63;
    const int b  = blockIdx.x >> 5;          // 32 blocks per batch
    const int i0 = (blockIdx.x & 31) << 6;

    {
        const float4* s2v = (const float4*)(s2g + b * N_);
        float4* d4 = (float4*)s2_lds;
        d4[tid]       = s2v[tid];
        d4[tid + 256] = s2v[tid + 256];
    }
    if (tid < 64) s1_lds[tid] = s1g[b * N_ + i0 + tid];
    __syncthreads();

    // batch max(s2); lrelu monotone -> m_i = lrelu(s1_i + s2max)
    {
        float lm = -1e30f;
        for (int idx = tid; idx < N_; idx += 256) lm = fmaxf(lm, s2_lds[idx]);
        #pragma unroll
        for (int off = 32; off; off >>= 1) lm = fmaxf(lm, __shfl_xor(lm, off));
        if (lane == 0) redmax[wave] = lm;
    }
    __syncthreads();
    const float s2max = fmaxf(fmaxf(redmax[0], redmax[1]),
                              fmaxf(redmax[2], redmax[3]));

    // per-row m, 1/l: 4 threads per row, float4 LDS reads
    {
        const int i = tid >> 2, jo = tid & 3;
        const float s1v = s1_lds[i];
        const float vm = s1v + s2max;
        const float m = vm > 0.f ? vm : ALPHA * vm;
        float l = 0.f;
        for (int j4 = jo * 4; j4 < N_; j4 += 16) {
            float4 s = *(const float4*)&s2_lds[j4];
            float v0 = s1v + s.x, v1 = s1v + s.y, v2 = s1v + s.z, v3 = s1v + s.w;
            l += __expf(fmaxf(v0, ALPHA * v0) - m);
            l += __expf(fmaxf(v1, ALPHA * v1) - m);
            l += __expf(fmaxf(v2, ALPHA * v2) - m);
            l += __expf(fmaxf(v3, ALPHA * v3) - m);
        }
        l += __shfl_xor(l, 1);
        l += __shfl_xor(l, 2);
        if (jo == 0) { m_lds[i] = m; li_lds[i] = 1.f / l; }
    }
    __syncthreads();

    const int row16 = lane & 15;             // MFMA m index
    const int quad  = lane >> 4;             // MFMA k-group
    const int irow  = wave * 16 + row16;     // block-local row
    const float s1v = s1_lds[irow];
    const float mr  = m_lds[irow];
    const float lir = li_lds[irow];

    // B-fragment row pointers: n = g*16 + row16, k offset = quad*8
    const unsigned short* bptr[4];
    #pragma unroll
    for (int g = 0; g < 4; g++)
        bptr[g] = xwT + ((size_t)b * OUTF_ + g * 16 + row16) * N_ + quad * 8;

    float* attp = out_att + ((size_t)(b * N_ + i0 + irow)) * N_ + quad * 8;
    const float* s2q = s2_lds + quad * 8;

    f32x4 acc0 = {0.f,0.f,0.f,0.f}, acc1 = {0.f,0.f,0.f,0.f};
    f32x4 acc2 = {0.f,0.f,0.f,0.f}, acc3 = {0.f,0.f,0.f,0.f};

    uint4 bnext[4];
    #pragma unroll
    for (int g = 0; g < 4; g++) bnext[g] = *(const uint4*)bptr[g];

    for (int jt = 0; jt < N_; jt += 32) {
        uint4 bc0 = bnext[0], bc1 = bnext[1], bc2 = bnext[2], bc3 = bnext[3];
        const int jn = (jt + 32) & (N_ - 1);   // wrap: last prefetch harmless
        #pragma unroll
        for (int g = 0; g < 4; g++) bnext[g] = *(const uint4*)(bptr[g] + jn);

        // att values for (row16, j = jt + quad*8 + jj) — A-frag layout
        float4 sa = *(const float4*)(s2q + jt);
        float4 sb = *(const float4*)(s2q + jt + 4);
        float av8[8];
        {
            float v;
            v = s1v + sa.x; av8[0] = __expf(fmaxf(v, ALPHA * v) - mr) * lir;
            v = s1v + sa.y; av8[1] = __expf(fmaxf(v, ALPHA * v) - mr) * lir;
            v = s1v + sa.z; av8[2] = __expf(fmaxf(v, ALPHA * v) - mr) * lir;
            v = s1v + sa.w; av8[3] = __expf(fmaxf(v, ALPHA * v) - mr) * lir;
            v = s1v + sb.x; av8[4] = __expf(fmaxf(v, ALPHA * v) - mr) * lir;
            v = s1v + sb.y; av8[5] = __expf(fmaxf(v, ALPHA * v) - mr) * lir;
            v = s1v + sb.z; av8[6] = __expf(fmaxf(v, ALPHA * v) - mr) * lir;
            v = s1v + sb.w; av8[7] = __expf(fmaxf(v, ALPHA * v) - mr) * lir;
        }
        // fp32 attention out: 8 contiguous floats per lane
        *(float4*)(attp + jt)     = make_float4(av8[0], av8[1], av8[2], av8[3]);
        *(float4*)(attp + jt + 4) = make_float4(av8[4], av8[5], av8[6], av8[7]);

        short8 a8;
        #pragma unroll
        for (int jj = 0; jj < 8; jj++) a8[jj] = (short)f2bf(av8[jj]);

        acc0 = __builtin_amdgcn_mfma_f32_16x16x32_bf16(a8, *(short8*)&bc0, acc0, 0, 0, 0);
        acc1 = __builtin_amdgcn_mfma_f32_16x16x32_bf16(a8, *(short8*)&bc1, acc1, 0, 0, 0);
        acc2 = __builtin_amdgcn_mfma_f32_16x16x32_bf16(a8, *(short8*)&bc2, acc2, 0, 0, 0);
        acc3 = __builtin_amdgcn_mfma_f32_16x16x32_bf16(a8, *(short8*)&bc3, acc3, 0, 0, 0);
    }

    // epilogue: D[row=quad*4+r][col=row16] for col-group g; relu, fp32 store
    {
        const size_t hb = ((size_t)(b * N_) + i0 + wave * 16) * OUTF_;
        #pragma unroll
        for (int r = 0; r < 4; r++) {
            const size_t ro = hb + (size_t)(quad * 4 + r) * OUTF_ + row16;
            out_h[ro]      = fmaxf(acc0[r], 0.f);
            out_h[ro + 16] = fmaxf(acc1[r], 0.f);
            out_h[ro + 32] = fmaxf(acc2[r], 0.f);
            out_h[ro + 48] = fmaxf(acc3[r], 0.f);
        }
    }
}

extern "C" void kernel_launch(void* const* d_in, const int* in_sizes, int n_in,
                              void* d_out, int out_size, void* d_ws, size_t ws_size,
                              hipStream_t stream) {
    const float* inp   = (const float*)d_in[0];
    const float* nodes = (const float*)d_in[1];
    const float* Wm    = (const float*)d_in[2];
    const float* av    = (const float*)d_in[3];

    float* out_h   = (float*)d_out;                                // [8,2048,64]
    float* out_att = out_h + (size_t)B_ * N_ * OUTF_;              // [8,2048,2048]

    // ws: xwT bf16 [8][64][2048] (2 MB) | s1 fp32 (64 KB) | s2 fp32 (64 KB)
    unsigned short* xwT = (unsigned short*)d_ws;
    float* s1_ws = (float*)((char*)d_ws + (size_t)B_ * OUTF_ * N_ * sizeof(unsigned short));
    float* s2_ws = s1_ws + (size_t)B_ * N_;

    prep_kernel<<<(B_ * N_) / 16, 256, 0, stream>>>(inp, nodes, Wm, av,
                                                    xwT, s1_ws, s2_ws);
    attn_kernel<<<(B_ * N_) / 64, 256, 0, stream>>>(xwT, s1_ws, s2_ws,
                                                    out_h, out_att);
}